// Round 7
// baseline (3515.770 us; speedup 1.0000x reference)
//
#include <hip/hip_runtime.h>
#include <math.h>

typedef _Float16 f16;
typedef _Float16 f16x8 __attribute__((ext_vector_type(8)));
typedef float    f32x4 __attribute__((ext_vector_type(4)));

#define BATCH 256
#define SEQ   1024
#define DI    128
#define DH    128
#define DM    144
#define NTH   768
#define MR    16
#define SXS   136   // f16 stride, 128-col activation panels
#define SYS   168   // f16 stride, 160-col (144+pad) panels
#define SZS   132   // f32 stride
#define PGS   20    // f32 stride per n-col of xproj partial buffers ([n][m] layout)

#define MFMA16(a, b, c) __builtin_amdgcn_mfma_f32_16x16x32_f16((a), (b), (c), 0, 0, 0)

__device__ __forceinline__ float sigm(float x) { return 1.f / (1.f + __expf(-x)); }
__device__ __forceinline__ float tanh_fast(float x) {
    const float e = __expf(2.f * x);
    return 1.f - 2.f / (e + 1.f);
}
// LDS-only barrier: global loads/stores stay in flight (T4).
__device__ __forceinline__ void bar_lds() {
    asm volatile("s_waitcnt lgkmcnt(0)" ::: "memory");
    __builtin_amdgcn_s_barrier();
}

__global__ __launch_bounds__(NTH, 3)
void hgru_kernel(
    const float* __restrict__ inputs,
    const float* __restrict__ r_w, const float* __restrict__ r_b,
    const float* __restrict__ z_w, const float* __restrict__ z_b,
    const float* __restrict__ h_w0, const float* __restrict__ h_b0,
    const float* __restrict__ h_w1, const float* __restrict__ h_b1,
    const float* __restrict__ h_w2, const float* __restrict__ h_b2,
    float* __restrict__ out, float* __restrict__ hid_out)
{
    __shared__ __align__(16) f16   sx [MR * SXS];     // x_{t+1} panel
    __shared__ __align__(16) f16   sh16[MR * SXS];    // h (f16 A-panel)
    __shared__ __align__(16) f16   srh[MR * SXS];     // r*h A-panel
    __shared__ __align__(16) f16   sy0[MR * SYS];     // mlp act1 (padded to 160)
    __shared__ __align__(16) f16   sy1[MR * SYS];     // mlp act2
    __shared__ __align__(16) float sz [MR * SZS];     // z gate f32
    __shared__ __align__(16) float shf[MR * SZS];     // master h state f32
    __shared__ __align__(16) float pg[2][256 * PGS];  // gate x-partials [n][m], dbuf
    __shared__ __align__(16) float pm[2][DM  * PGS];  // mlp0 x-partials [n][m], dbuf

    const int tid  = threadIdx.x;
    const int w    = tid >> 6;      // wave 0..11
    const int lane = tid & 63;
    const int ln   = lane & 15;
    const int kg   = lane >> 4;     // C rows = 4*kg..4*kg+3
    const int b0   = blockIdx.x * MR;
    const bool is_h = (w < 8);

    // ---------------- zero-init LDS ----------------
    for (int i = tid; i < MR * SYS; i += NTH) { sy0[i] = (f16)0.f; sy1[i] = (f16)0.f; }
    for (int i = tid; i < MR * SXS; i += NTH) { sh16[i] = (f16)0.f; }
    for (int i = tid; i < MR * SZS; i += NTH) { shf[i] = 0.f; }

    if (is_h) {
        // ============================ h-waves ============================
        const int col = w * 16 + ln;

        f16x8 wrh[4], wzh[4], w0h[4], w0h8[4], w1f[5], w1f8[5], w2f[5];
        #pragma unroll
        for (int kt = 0; kt < 4; ++kt) {
            f16x8 a, b, c, d;
            #pragma unroll
            for (int j = 0; j < 8; ++j) {
                const int k = DI + kt * 32 + kg * 8 + j;
                a[j] = (f16)r_w[(size_t)k * DH + col];
                b[j] = (f16)z_w[(size_t)k * DH + col];
                c[j] = (f16)h_w0[(size_t)k * DM + col];
                d[j] = (w == 0) ? (f16)h_w0[(size_t)k * DM + 128 + ln] : (f16)0.f;
            }
            wrh[kt] = a; wzh[kt] = b; w0h[kt] = c; w0h8[kt] = d;
        }
        #pragma unroll
        for (int kt = 0; kt < 5; ++kt) {
            f16x8 a, b, c;
            #pragma unroll
            for (int j = 0; j < 8; ++j) {
                const int k = kt * 32 + kg * 8 + j;
                const bool in = (k < DM);
                a[j] = in ? (f16)h_w1[(size_t)k * DM + col] : (f16)0.f;
                b[j] = (w == 1 && in) ? (f16)h_w1[(size_t)k * DM + 128 + ln] : (f16)0.f;
                c[j] = in ? (f16)h_w2[(size_t)k * DH + col] : (f16)0.f;
            }
            w1f[kt] = a; w1f8[kt] = b; w2f[kt] = c;
        }
        const float b1r = r_b[col], b1z = z_b[col];
        const float b2  = h_b0[col], b28 = h_b0[128 + ln];
        const float b3  = h_b1[col], b38 = h_b1[128 + ln];
        const float b4  = h_b2[col];

        float* op[4];
        #pragma unroll
        for (int j = 0; j < 4; ++j)
            op[j] = out + (size_t)(b0 + 4 * kg + j) * SEQ * DH + col;

        bar_lds();   // x-waves: sx(0) published (+ zero-init visible)
        bar_lds();   // x-waves: xproj(0) -> pg[0]/pm[0] done

        for (int t = 0; t < SEQ; ++t) {
            const int pb = t & 1;

            // ---- s1: r gate (C-in = x-partial from producer waves) ----
            f16x8 ha[4];
            #pragma unroll
            for (int kt = 0; kt < 4; ++kt)
                ha[kt] = *(const f16x8*)(sh16 + ln * SXS + kt * 32 + kg * 8);
            f32x4 acc = *(const f32x4*)(pg[pb] + (unsigned)col * PGS + kg * 4);
            #pragma unroll
            for (int kt = 0; kt < 4; ++kt) acc = MFMA16(ha[kt], wrh[kt], acc);
            #pragma unroll
            for (int j = 0; j < 4; ++j) {
                const int m = 4 * kg + j;
                const float g = sigm(acc[j] + b1r);
                srh[m * SXS + col] = (f16)(g * shf[m * SZS + col]);
            }
            bar_lds(); // A

            // ---- s2: z h-part (shadow) + y0 ----
            f32x4 pz = *(const f32x4*)(pg[pb] + (unsigned)(128 + col) * PGS + kg * 4);
            #pragma unroll
            for (int kt = 0; kt < 4; ++kt) pz = MFMA16(ha[kt], wzh[kt], pz);

            f16x8 ra[4];
            #pragma unroll
            for (int kt = 0; kt < 4; ++kt)
                ra[kt] = *(const f16x8*)(srh + ln * SXS + kt * 32 + kg * 8);
            f32x4 a0 = *(const f32x4*)(pm[pb] + (unsigned)col * PGS + kg * 4);
            #pragma unroll
            for (int kt = 0; kt < 4; ++kt) a0 = MFMA16(ra[kt], w0h[kt], a0);
            #pragma unroll
            for (int j = 0; j < 4; ++j)
                sy0[(4 * kg + j) * SYS + col] = (f16)fmaxf(a0[j] + b2, 0.f);
            if (w == 0) {
                f32x4 a8 = *(const f32x4*)(pm[pb] + (unsigned)(128 + ln) * PGS + kg * 4);
                #pragma unroll
                for (int kt = 0; kt < 4; ++kt) a8 = MFMA16(ra[kt], w0h8[kt], a8);
                #pragma unroll
                for (int j = 0; j < 4; ++j)
                    sy0[(4 * kg + j) * SYS + 128 + ln] = (f16)fmaxf(a8[j] + b28, 0.f);
            }
            bar_lds(); // B

            // ---- s3: y1 + z sigmoid epilogue ----
            f16x8 ya[5];
            #pragma unroll
            for (int kt = 0; kt < 5; ++kt)
                ya[kt] = *(const f16x8*)(sy0 + ln * SYS + kt * 32 + kg * 8);
            f32x4 a1 = {0.f, 0.f, 0.f, 0.f};
            #pragma unroll
            for (int kt = 0; kt < 5; ++kt) a1 = MFMA16(ya[kt], w1f[kt], a1);
            #pragma unroll
            for (int j = 0; j < 4; ++j)
                sy1[(4 * kg + j) * SYS + col] = (f16)fmaxf(a1[j] + b3, 0.f);
            if (w == 1) {
                f32x4 a8 = {0.f, 0.f, 0.f, 0.f};
                #pragma unroll
                for (int kt = 0; kt < 5; ++kt) a8 = MFMA16(ya[kt], w1f8[kt], a8);
                #pragma unroll
                for (int j = 0; j < 4; ++j)
                    sy1[(4 * kg + j) * SYS + 128 + ln] = (f16)fmaxf(a8[j] + b38, 0.f);
            }
            #pragma unroll
            for (int j = 0; j < 4; ++j)
                sz[(4 * kg + j) * SZS + col] = sigm(pz[j] + b1z);
            bar_lds(); // C

            // ---- s4: h~ and h update ----
            f16x8 za[5];
            #pragma unroll
            for (int kt = 0; kt < 5; ++kt)
                za[kt] = *(const f16x8*)(sy1 + ln * SYS + kt * 32 + kg * 8);
            f32x4 a2 = {0.f, 0.f, 0.f, 0.f};
            #pragma unroll
            for (int kt = 0; kt < 5; ++kt) a2 = MFMA16(za[kt], w2f[kt], a2);
            #pragma unroll
            for (int j = 0; j < 4; ++j) {
                const int m = 4 * kg + j;
                const float ht = tanh_fast(a2[j] + b4);
                const float zz = sz[m * SZS + col];
                const float hn = (1.f - zz) * shf[m * SZS + col] + zz * ht;
                shf[m * SZS + col] = hn;
                sh16[m * SXS + col] = (f16)hn;
                *op[j] = hn; op[j] += DH;   // floats in VMEM queue across barriers
            }
            bar_lds(); // D
        }
    } else {
        // ============================ x-waves (producers) ============================
        const int xw = w - 8;                 // 0..3
        const int n0 = (xw == 0) ? 3 : 2;     // w0x tiles owned

        f16x8 wgx[4][4];                      // gate tiles 4*xw..4*xw+3 (r:0-7, z:8-15)
        #pragma unroll
        for (int i = 0; i < 4; ++i) {
            const int gt = 4 * xw + i;
            const float* __restrict__ W = (gt < 8) ? r_w : z_w;
            const int gcol = (gt & 7) * 16 + ln;
            #pragma unroll
            for (int kt = 0; kt < 4; ++kt) {
                f16x8 f;
                #pragma unroll
                for (int j = 0; j < 8; ++j)
                    f[j] = (f16)W[(size_t)(kt * 32 + kg * 8 + j) * DH + gcol];
                wgx[i][kt] = f;
            }
        }
        f16x8 w0x[3][4];
        int mtile[3]; mtile[0] = xw; mtile[1] = xw + 4; mtile[2] = 8;
        #pragma unroll
        for (int i = 0; i < 3; ++i) if (i < n0) {
            const int mcol = mtile[i] * 16 + ln;
            #pragma unroll
            for (int kt = 0; kt < 4; ++kt) {
                f16x8 f;
                #pragma unroll
                for (int j = 0; j < 8; ++j)
                    f[j] = (f16)h_w0[(size_t)(kt * 32 + kg * 8 + j) * DM + mcol];
                w0x[i][kt] = f;
            }
        }

        // x staging: 256 threads cover 16 rows x 16 segments of 8 f16
        const int xt   = tid & 255;
        const int xrow = xt >> 4;
        const int xseg = xt & 15;
        const float* __restrict__ xbase = inputs + (size_t)(b0 + xrow) * SEQ * DI + xseg * 8;

        {   // publish x(0)
            const float4 a = ((const float4*)xbase)[0];
            const float4 b = ((const float4*)(xbase + 4))[0];
            f16x8 v; v[0]=(f16)a.x; v[1]=(f16)a.y; v[2]=(f16)a.z; v[3]=(f16)a.w;
                     v[4]=(f16)b.x; v[5]=(f16)b.y; v[6]=(f16)b.z; v[7]=(f16)b.w;
            *(f16x8*)(sx + xrow * SXS + xseg * 8) = v;
        }
        float4 xpA0 = ((const float4*)(xbase + (size_t)1 * DI))[0];
        float4 xpA1 = ((const float4*)(xbase + (size_t)1 * DI + 4))[0];

        bar_lds();   // sx(0) visible

        {   // xproj(0) -> pg[0]/pm[0]
            f16x8 xa[4];
            #pragma unroll
            for (int kt = 0; kt < 4; ++kt)
                xa[kt] = *(const f16x8*)(sx + ln * SXS + kt * 32 + kg * 8);
            #pragma unroll
            for (int i = 0; i < 4; ++i) {
                const int gt = 4 * xw + i;
                f32x4 a = {0.f, 0.f, 0.f, 0.f};
                #pragma unroll
                for (int kt = 0; kt < 4; ++kt) a = MFMA16(xa[kt], wgx[i][kt], a);
                *(f32x4*)(pg[0] + (unsigned)(gt * 16 + ln) * PGS + kg * 4) = a;
            }
            #pragma unroll
            for (int i = 0; i < 3; ++i) if (i < n0) {
                f32x4 a = {0.f, 0.f, 0.f, 0.f};
                #pragma unroll
                for (int kt = 0; kt < 4; ++kt) a = MFMA16(xa[kt], w0x[i][kt], a);
                *(f32x4*)(pm[0] + (unsigned)(mtile[i] * 16 + ln) * PGS + kg * 4) = a;
            }
        }
        bar_lds();   // xproj(0) visible

        for (int t = 0; t < SEQ; ++t) {
            const int nb = (t + 1) & 1;

            // publish x(t+1) (own reads of sx(t) finished before barD(t-1))
            {
                f16x8 v; v[0]=(f16)xpA0.x; v[1]=(f16)xpA0.y; v[2]=(f16)xpA0.z; v[3]=(f16)xpA0.w;
                         v[4]=(f16)xpA1.x; v[5]=(f16)xpA1.y; v[6]=(f16)xpA1.z; v[7]=(f16)xpA1.w;
                *(f16x8*)(sx + xrow * SXS + xseg * 8) = v;
            }
            const int tn = (t + 2 < SEQ) ? t + 2 : SEQ - 1;
            const float4 xpB0 = ((const float4*)(xbase + (size_t)tn * DI))[0];
            const float4 xpB1 = ((const float4*)(xbase + (size_t)tn * DI + 4))[0];
            bar_lds(); // A

            // compute xproj(t+1) into buf nb (deadline: barrier D)
            f16x8 xa[4];
            #pragma unroll
            for (int kt = 0; kt < 4; ++kt)
                xa[kt] = *(const f16x8*)(sx + ln * SXS + kt * 32 + kg * 8);
            #pragma unroll
            for (int i = 0; i < 4; ++i) {
                const int gt = 4 * xw + i;
                f32x4 a = {0.f, 0.f, 0.f, 0.f};
                #pragma unroll
                for (int kt = 0; kt < 4; ++kt) a = MFMA16(xa[kt], wgx[i][kt], a);
                *(f32x4*)(pg[nb] + (unsigned)(gt * 16 + ln) * PGS + kg * 4) = a;
            }
            #pragma unroll
            for (int i = 0; i < 3; ++i) if (i < n0) {
                f32x4 a = {0.f, 0.f, 0.f, 0.f};
                #pragma unroll
                for (int kt = 0; kt < 4; ++kt) a = MFMA16(xa[kt], w0x[i][kt], a);
                *(f32x4*)(pm[nb] + (unsigned)(mtile[i] * 16 + ln) * PGS + kg * 4) = a;
            }
            bar_lds(); // B
            bar_lds(); // C
            bar_lds(); // D

            xpA0 = xpB0; xpA1 = xpB1;
        }
    }

    // final hidden state (shf synced by last barrier D)
    for (int i = tid; i < MR * DH; i += NTH)
        hid_out[(size_t)(b0 + (i >> 7)) * DH + (i & 127)] = shf[(i >> 7) * SZS + (i & 127)];
}

extern "C" void kernel_launch(void* const* d_in, const int* in_sizes, int n_in,
                              void* d_out, int out_size, void* d_ws, size_t ws_size,
                              hipStream_t stream) {
    const float* inputs = (const float*)d_in[0];
    const float* r_w  = (const float*)d_in[1];
    const float* r_b  = (const float*)d_in[2];
    const float* z_w  = (const float*)d_in[3];
    const float* z_b  = (const float*)d_in[4];
    const float* h_w0 = (const float*)d_in[5];
    const float* h_b0 = (const float*)d_in[6];
    const float* h_w1 = (const float*)d_in[7];
    const float* h_b1 = (const float*)d_in[8];
    const float* h_w2 = (const float*)d_in[9];
    const float* h_b2 = (const float*)d_in[10];

    float* out = (float*)d_out;
    float* hid = out + (size_t)BATCH * SEQ * DH;

    hipLaunchKernelGGL(hgru_kernel, dim3(BATCH / MR), dim3(NTH), 0, stream,
                       inputs, r_w, r_b, z_w, z_b,
                       h_w0, h_b0, h_w1, h_b1, h_w2, h_b2,
                       out, hid);
}

// Round 8
// 2352.012 us; speedup vs baseline: 1.4948x; 1.4948x over previous
//
#include <hip/hip_runtime.h>
#include <math.h>

typedef _Float16 f16;
typedef _Float16 f16x8 __attribute__((ext_vector_type(8)));
typedef float    f32x4 __attribute__((ext_vector_type(4)));

#define BATCH 256
#define SEQ   1024
#define DI    128
#define DH    128
#define DM    144
#define NTH   512
#define MR    16
// Row strides tuned so the 4 kg row-groups (rows 4*kg+j) hit disjoint bank
// quads on epilogue writes: need 4*stride = 8 mod 32 (dwords).
#define SXS   132   // f16: 66 dw/row, 4*66=264=8 mod 32  ✓
#define SYS   164   // f16: 82 dw/row, 4*82=328=8 mod 32  ✓
#define SZS   134   // f32: 134 dw/row, 4*134=536=24 mod 32 ✓ (distinct)
#define PGS   20    // f32 partials [n][m]: 16B-aligned rows (80B)

#define MFMA16(a, b, c) __builtin_amdgcn_mfma_f32_16x16x32_f16((a), (b), (c), 0, 0, 0)

__device__ __forceinline__ float sigm(float x) { return 1.f / (1.f + __expf(-x)); }
__device__ __forceinline__ float tanh_fast(float x) {
    const float e = __expf(2.f * x);
    return 1.f - 2.f / (e + 1.f);
}
// LDS-only barrier: global loads/stores stay in flight (T4).
__device__ __forceinline__ void bar_lds() {
    asm volatile("s_waitcnt lgkmcnt(0)" ::: "memory");
    __builtin_amdgcn_s_barrier();
}

__global__ __launch_bounds__(NTH, 2) __attribute__((amdgpu_waves_per_eu(2, 2)))
void hgru_kernel(
    const float* __restrict__ inputs,
    const float* __restrict__ r_w, const float* __restrict__ r_b,
    const float* __restrict__ z_w, const float* __restrict__ z_b,
    const float* __restrict__ h_w0, const float* __restrict__ h_b0,
    const float* __restrict__ h_w1, const float* __restrict__ h_b1,
    const float* __restrict__ h_w2, const float* __restrict__ h_b2,
    float* __restrict__ out, float* __restrict__ hid_out)
{
    __shared__ __align__(16) f16   sx [MR * SXS];   // x_{t+1} panel
    __shared__ __align__(16) f16   sh16[MR * SXS];  // h (f16 A-panel)
    __shared__ __align__(16) f16   srh[MR * SXS];   // r*h A-panel
    __shared__ __align__(16) f16   sy0[MR * SYS];   // mlp act1 (padded to 160)
    __shared__ __align__(16) f16   sy1[MR * SYS];   // mlp act2
    __shared__ __align__(16) float sz [MR * SZS];   // z gate f32
    __shared__ __align__(16) float shf[MR * SZS];   // master h state f32
    __shared__ __align__(16) float pg[256 * PGS];   // gate x-partials [n][m] (r:0-127,z:128-255)
    __shared__ __align__(16) float pm[DM  * PGS];   // mlp0 x-partials [n][m]

    const int tid  = threadIdx.x;
    const int w    = tid >> 6;      // wave 0..7
    const int lane = tid & 63;
    const int ln   = lane & 15;
    const int kg   = lane >> 4;     // C rows 4*kg..4*kg+3
    const int b0   = blockIdx.x * MR;
    const int col  = w * 16 + ln;   // this wave's N-column

    // ---------------- zero-init LDS ----------------
    for (int i = tid; i < MR * SYS; i += NTH) { sy0[i] = (f16)0.f; sy1[i] = (f16)0.f; }
    for (int i = tid; i < MR * SXS; i += NTH) { sh16[i] = (f16)0.f; }
    for (int i = tid; i < MR * SZS; i += NTH) { shf[i] = 0.f; }

    // ---------------- register weight fragments ----------------
    // B-frag convention (verified r3-r6): elem j = W[kt*32 + kg*8 + j][col]
    f16x8 wrh[4], wzh[4], w0h[4], wrx[4], wzx[4], w0x[4];
    #pragma unroll
    for (int kt = 0; kt < 4; ++kt) {
        f16x8 a, b, c, d, e, f;
        #pragma unroll
        for (int j = 0; j < 8; ++j) {
            const int k = kt * 32 + kg * 8 + j;
            a[j] = (f16)r_w [(size_t)(DI + k) * DH + col];
            b[j] = (f16)z_w [(size_t)(DI + k) * DH + col];
            c[j] = (f16)h_w0[(size_t)(DI + k) * DM + col];
            d[j] = (f16)r_w [(size_t)k * DH + col];
            e[j] = (f16)z_w [(size_t)k * DH + col];
            f[j] = (f16)h_w0[(size_t)k * DM + col];
        }
        wrh[kt] = a; wzh[kt] = b; w0h[kt] = c; wrx[kt] = d; wzx[kt] = e; w0x[kt] = f;
    }
    f16x8 w1f[5], w2f[5];
    #pragma unroll
    for (int kt = 0; kt < 5; ++kt) {
        f16x8 a, b;
        #pragma unroll
        for (int j = 0; j < 8; ++j) {
            const int k = kt * 32 + kg * 8 + j;
            const bool in = (k < DM);
            a[j] = in ? (f16)h_w1[(size_t)k * DM + col] : (f16)0.f;
            b[j] = in ? (f16)h_w2[(size_t)k * DH + col] : (f16)0.f;
        }
        w1f[kt] = a; w2f[kt] = b;
    }
    // shared "extra tile 8" array: w0 -> y0 tile8 (h-rows of h_w0),
    // w1 -> y1 tile8 (h_w1), w2 -> pm tile8 shadow (x-rows of h_w0)
    f16x8 ext[5];
    #pragma unroll
    for (int kt = 0; kt < 5; ++kt) {
        f16x8 f;
        #pragma unroll
        for (int j = 0; j < 8; ++j) {
            const int k = kt * 32 + kg * 8 + j;
            float v = 0.f;
            if (w == 0 && kt < 4)      v = (float)h_w0[(size_t)(DI + k) * DM + 128 + ln];
            else if (w == 1 && k < DM) v = (float)h_w1[(size_t)k * DM + 128 + ln];
            else if (w == 2 && kt < 4) v = (float)h_w0[(size_t)k * DM + 128 + ln];
            f[j] = (f16)v;
        }
        ext[kt] = f;
    }

    const float b1r = r_b[col], b1z = z_b[col];
    const float b2  = h_b0[col], b3 = h_b1[col], b4 = h_b2[col];
    const float bext = (w == 0) ? h_b0[128 + ln] : (w == 1) ? h_b1[128 + ln] : 0.f;

    float* op[4];
    #pragma unroll
    for (int j = 0; j < 4; ++j)
        op[j] = out + (size_t)(b0 + 4 * kg + j) * SEQ * DH + col;

    // ---------------- x staging (waves 0-3) ----------------
    const bool xldr = (tid < 256);
    const int  xrow = tid >> 4;
    const int  xseg = tid & 15;
    const float* __restrict__ xbase = inputs + (size_t)(b0 + (xrow & 15)) * SEQ * DI + xseg * 8;

    float4 xpA0 = {0,0,0,0}, xpA1 = {0,0,0,0};
    if (xldr) {   // publish x(0); prefetch x(1)
        const float4 a = ((const float4*)xbase)[0];
        const float4 b = ((const float4*)(xbase + 4))[0];
        f16x8 v; v[0]=(f16)a.x; v[1]=(f16)a.y; v[2]=(f16)a.z; v[3]=(f16)a.w;
                 v[4]=(f16)b.x; v[5]=(f16)b.y; v[6]=(f16)b.z; v[7]=(f16)b.w;
        *(f16x8*)(sx + xrow * SXS + xseg * 8) = v;
        xpA0 = ((const float4*)(xbase + (size_t)1 * DI))[0];
        xpA1 = ((const float4*)(xbase + (size_t)1 * DI + 4))[0];
    }
    bar_lds();

    // ---- xproj(0) into pg/pm ----
    {
        f16x8 xa[4];
        #pragma unroll
        for (int kt = 0; kt < 4; ++kt)
            xa[kt] = *(const f16x8*)(sx + ln * SXS + kt * 32 + kg * 8);
        f32x4 a = {0,0,0,0};
        #pragma unroll
        for (int kt = 0; kt < 4; ++kt) a = MFMA16(xa[kt], wrx[kt], a);
        *(f32x4*)(pg + (unsigned)col * PGS + kg * 4) = a;
        f32x4 b = {0,0,0,0};
        #pragma unroll
        for (int kt = 0; kt < 4; ++kt) b = MFMA16(xa[kt], wzx[kt], b);
        *(f32x4*)(pg + (unsigned)(128 + col) * PGS + kg * 4) = b;
        f32x4 c = {0,0,0,0};
        #pragma unroll
        for (int kt = 0; kt < 4; ++kt) c = MFMA16(xa[kt], w0x[kt], c);
        *(f32x4*)(pm + (unsigned)col * PGS + kg * 4) = c;
        if (w == 2) {
            f32x4 d = {0,0,0,0};
            #pragma unroll
            for (int kt = 0; kt < 4; ++kt) d = MFMA16(xa[kt], ext[kt], d);
            *(f32x4*)(pm + (unsigned)(128 + ln) * PGS + kg * 4) = d;
        }
    }
    bar_lds();

    for (int t = 0; t < SEQ; ++t) {
        // prefetch x(t+2): stays in flight across lgkm-only barriers
        float4 xpB0, xpB1;
        if (xldr) {
            const int tn = (t + 2 < SEQ) ? t + 2 : SEQ - 1;
            xpB0 = ((const float4*)(xbase + (size_t)tn * DI))[0];
            xpB1 = ((const float4*)(xbase + (size_t)tn * DI + 4))[0];
        }

        // ======== s1 (critical, short): r gate only ========
        f16x8 ha[4];
        #pragma unroll
        for (int kt = 0; kt < 4; ++kt)
            ha[kt] = *(const f16x8*)(sh16 + ln * SXS + kt * 32 + kg * 8);
        f32x4 ar = *(const f32x4*)(pg + (unsigned)col * PGS + kg * 4);
        #pragma unroll
        for (int kt = 0; kt < 4; ++kt) ar = MFMA16(ha[kt], wrh[kt], ar);
        #pragma unroll
        for (int j = 0; j < 4; ++j) {
            const int m = 4 * kg + j;
            const float g = sigm(ar[j] + b1r);
            srh[m * SXS + col] = (f16)(g * shf[m * SZS + col]);
        }
        bar_lds(); // A

        // ======== s2: y0 (critical) + z h-part (shadow, reuses ha) ========
        f32x4 pz = *(const f32x4*)(pg + (unsigned)(128 + col) * PGS + kg * 4);
        #pragma unroll
        for (int kt = 0; kt < 4; ++kt) pz = MFMA16(ha[kt], wzh[kt], pz);

        f16x8 ra[4];
        #pragma unroll
        for (int kt = 0; kt < 4; ++kt)
            ra[kt] = *(const f16x8*)(srh + ln * SXS + kt * 32 + kg * 8);
        f32x4 a0 = *(const f32x4*)(pm + (unsigned)col * PGS + kg * 4);
        #pragma unroll
        for (int kt = 0; kt < 4; ++kt) a0 = MFMA16(ra[kt], w0h[kt], a0);
        #pragma unroll
        for (int j = 0; j < 4; ++j)
            sy0[(4 * kg + j) * SYS + col] = (f16)fmaxf(a0[j] + b2, 0.f);
        if (w == 0) {
            f32x4 a8 = *(const f32x4*)(pm + (unsigned)(128 + ln) * PGS + kg * 4);
            #pragma unroll
            for (int kt = 0; kt < 4; ++kt) a8 = MFMA16(ra[kt], ext[kt], a8);
            #pragma unroll
            for (int j = 0; j < 4; ++j)
                sy0[(4 * kg + j) * SYS + 128 + ln] = (f16)fmaxf(a8[j] + bext, 0.f);
        }
        // publish x(t+1)
        if (xldr) {
            f16x8 v; v[0]=(f16)xpA0.x; v[1]=(f16)xpA0.y; v[2]=(f16)xpA0.z; v[3]=(f16)xpA0.w;
                     v[4]=(f16)xpA1.x; v[5]=(f16)xpA1.y; v[6]=(f16)xpA1.z; v[7]=(f16)xpA1.w;
            *(f16x8*)(sx + xrow * SXS + xseg * 8) = v;
        }
        bar_lds(); // B

        // ======== s3: y1 (critical) + z sigmoid + gates-x shadow ========
        f16x8 ya[5];
        #pragma unroll
        for (int kt = 0; kt < 5; ++kt)
            ya[kt] = *(const f16x8*)(sy0 + ln * SYS + kt * 32 + kg * 8);
        f32x4 a1 = {0,0,0,0};
        #pragma unroll
        for (int kt = 0; kt < 5; ++kt) a1 = MFMA16(ya[kt], w1f[kt], a1);
        #pragma unroll
        for (int j = 0; j < 4; ++j)
            sy1[(4 * kg + j) * SYS + col] = (f16)fmaxf(a1[j] + b3, 0.f);
        if (w == 1) {
            f32x4 a8 = {0,0,0,0};
            #pragma unroll
            for (int kt = 0; kt < 5; ++kt) a8 = MFMA16(ya[kt], ext[kt], a8);
            #pragma unroll
            for (int j = 0; j < 4; ++j)
                sy1[(4 * kg + j) * SYS + 128 + ln] = (f16)fmaxf(a8[j] + bext, 0.f);
        }
        #pragma unroll
        for (int j = 0; j < 4; ++j)
            sz[(4 * kg + j) * SZS + col] = sigm(pz[j] + b1z);
        // shadow: gates-x for step t+1 (single-buffered: consumers already read)
        f16x8 xa[4];
        #pragma unroll
        for (int kt = 0; kt < 4; ++kt)
            xa[kt] = *(const f16x8*)(sx + ln * SXS + kt * 32 + kg * 8);
        {
            f32x4 a = {0,0,0,0};
            #pragma unroll
            for (int kt = 0; kt < 4; ++kt) a = MFMA16(xa[kt], wrx[kt], a);
            *(f32x4*)(pg + (unsigned)col * PGS + kg * 4) = a;
            f32x4 b = {0,0,0,0};
            #pragma unroll
            for (int kt = 0; kt < 4; ++kt) b = MFMA16(xa[kt], wzx[kt], b);
            *(f32x4*)(pg + (unsigned)(128 + col) * PGS + kg * 4) = b;
        }
        bar_lds(); // C

        // ======== s4: h~ (critical) + mlp0-x shadow + h update ========
        f16x8 za[5];
        #pragma unroll
        for (int kt = 0; kt < 5; ++kt)
            za[kt] = *(const f16x8*)(sy1 + ln * SYS + kt * 32 + kg * 8);
        f32x4 a2 = {0,0,0,0};
        #pragma unroll
        for (int kt = 0; kt < 5; ++kt) a2 = MFMA16(za[kt], w2f[kt], a2);
        {
            f32x4 a = {0,0,0,0};
            #pragma unroll
            for (int kt = 0; kt < 4; ++kt) a = MFMA16(xa[kt], w0x[kt], a);
            *(f32x4*)(pm + (unsigned)col * PGS + kg * 4) = a;
            if (w == 2) {
                f32x4 d = {0,0,0,0};
                #pragma unroll
                for (int kt = 0; kt < 4; ++kt) d = MFMA16(xa[kt], ext[kt], d);
                *(f32x4*)(pm + (unsigned)(128 + ln) * PGS + kg * 4) = d;
            }
        }
        #pragma unroll
        for (int j = 0; j < 4; ++j) {
            const int m = 4 * kg + j;
            const float ht = tanh_fast(a2[j] + b4);
            const float zz = sz[m * SZS + col];
            const float hn = (1.f - zz) * shf[m * SZS + col] + zz * ht;
            shf[m * SZS + col] = hn;
            sh16[m * SXS + col] = (f16)hn;
            *op[j] = hn; op[j] += DH;    // fire-and-forget, no barrier drains it
        }
        bar_lds(); // D

        xpA0 = xpB0; xpA1 = xpB1;
    }

    for (int i = tid; i < MR * DH; i += NTH)
        hid_out[(size_t)(b0 + (i >> 7)) * DH + (i & 127)] = shf[(i >> 7) * SZS + (i & 127)];
}

extern "C" void kernel_launch(void* const* d_in, const int* in_sizes, int n_in,
                              void* d_out, int out_size, void* d_ws, size_t ws_size,
                              hipStream_t stream) {
    const float* inputs = (const float*)d_in[0];
    const float* r_w  = (const float*)d_in[1];
    const float* r_b  = (const float*)d_in[2];
    const float* z_w  = (const float*)d_in[3];
    const float* z_b  = (const float*)d_in[4];
    const float* h_w0 = (const float*)d_in[5];
    const float* h_b0 = (const float*)d_in[6];
    const float* h_w1 = (const float*)d_in[7];
    const float* h_b1 = (const float*)d_in[8];
    const float* h_w2 = (const float*)d_in[9];
    const float* h_b2 = (const float*)d_in[10];

    float* out = (float*)d_out;
    float* hid = out + (size_t)BATCH * SEQ * DH;

    hipLaunchKernelGGL(hgru_kernel, dim3(BATCH / MR), dim3(NTH), 0, stream,
                       inputs, r_w, r_b, z_w, z_b,
                       h_w0, h_b0, h_w1, h_b1, h_w2, h_b2,
                       out, hid);
}

// Round 9
// 2231.372 us; speedup vs baseline: 1.5756x; 1.0541x over previous
//
#include <hip/hip_runtime.h>
#include <math.h>

typedef _Float16 f16;
typedef _Float16 f16x8 __attribute__((ext_vector_type(8)));
typedef _Float16 f16x4 __attribute__((ext_vector_type(4)));
typedef float    f32x4 __attribute__((ext_vector_type(4)));

#define BATCH 256
#define SEQ   1024
#define DI    128
#define DH    128
#define DM    144
#define NTH   512
#define MR    16
#define SXS   132   // f16 panel stride (4*66 dw = 8 mod 32 -> kg groups on disjoint quads)
#define SYS   164   // f16 stride, 160-col panels
#define SZS   134   // f32 stride
#define PGS   20    // (fallback only) f32 partials stride
#define NW    400   // xproj cols: r 0-127, z 128-255, mlp0 256-399
// ws layout: f16 [rb(16)][t(1024)][n(400)][m(16)]
#define WS_ELEMS ((size_t)16 * SEQ * NW * 16)

#define MFMA16(a, b, c) __builtin_amdgcn_mfma_f32_16x16x32_f16((a), (b), (c), 0, 0, 0)

__device__ __forceinline__ float sigm(float x) { return 1.f / (1.f + __expf(-x)); }
__device__ __forceinline__ float tanh_fast(float x) {
    const float e = __expf(2.f * x);
    return 1.f - 2.f / (e + 1.f);
}
__device__ __forceinline__ void bar_lds() {
    asm volatile("s_waitcnt lgkmcnt(0)" ::: "memory");
    __builtin_amdgcn_s_barrier();
}
__device__ __forceinline__ f32x4 cvt4(f16x4 v) {
    f32x4 r; r[0] = (float)v[0]; r[1] = (float)v[1]; r[2] = (float)v[2]; r[3] = (float)v[3];
    return r;
}

// ===================== pre-pass: xproj = x @ [r_w | z_w | h_w0] (x-rows) =====================
__global__ __launch_bounds__(512, 2) void xproj_kernel(
    const float* __restrict__ inputs,
    const float* __restrict__ r_w, const float* __restrict__ z_w,
    const float* __restrict__ h_w0, f16* __restrict__ ws)
{
    __shared__ __align__(16) f16 lx[16 * SXS];

    const int rb = blockIdx.x >> 5;        // 0..15 batch row-block
    const int tc = blockIdx.x & 31;        // 0..31 time chunk (32 steps)
    const int tid = threadIdx.x;
    const int w   = tid >> 6;
    const int ln  = tid & 15;
    const int kg  = (tid & 63) >> 4;
    const int b0  = rb * MR;

    // wave w owns n-tiles {w, w+8, w+16, (w==0: 24)}
    const int nt = (w == 0) ? 4 : 3;
    f16x8 wb[4][4];
    #pragma unroll
    for (int i = 0; i < 4; ++i) if (i < nt) {
        const int tile = w + 8 * i;
        #pragma unroll
        for (int kt = 0; kt < 4; ++kt) {
            f16x8 f;
            #pragma unroll
            for (int j = 0; j < 8; ++j) {
                const int k = kt * 32 + kg * 8 + j;
                float v;
                if (tile < 8)       v = r_w [(size_t)k * DH + tile * 16 + ln];
                else if (tile < 16) v = z_w [(size_t)k * DH + (tile - 8) * 16 + ln];
                else                v = h_w0[(size_t)k * DM + (tile - 16) * 16 + ln];
                f[j] = (f16)v;
            }
            wb[i][kt] = f;
        }
    }

    for (int tt = 0; tt < 32; ++tt) {
        const int t = tc * 32 + tt;
        if (tid < 256) {
            const int row = tid >> 4, seg = tid & 15;
            const float* xb = inputs + ((size_t)(b0 + row) * SEQ + t) * DI + seg * 8;
            const float4 a = ((const float4*)xb)[0];
            const float4 b = ((const float4*)(xb + 4))[0];
            f16x8 v; v[0]=(f16)a.x; v[1]=(f16)a.y; v[2]=(f16)a.z; v[3]=(f16)a.w;
                     v[4]=(f16)b.x; v[5]=(f16)b.y; v[6]=(f16)b.z; v[7]=(f16)b.w;
            *(f16x8*)(lx + row * SXS + seg * 8) = v;
        }
        __syncthreads();
        f16x8 xa[4];
        #pragma unroll
        for (int kt = 0; kt < 4; ++kt)
            xa[kt] = *(const f16x8*)(lx + ln * SXS + kt * 32 + kg * 8);
        #pragma unroll
        for (int i = 0; i < 4; ++i) if (i < nt) {
            const int tile = w + 8 * i;
            f32x4 a = {0.f, 0.f, 0.f, 0.f};
            #pragma unroll
            for (int kt = 0; kt < 4; ++kt) a = MFMA16(xa[kt], wb[i][kt], a);
            f16x4 o; o[0]=(f16)a[0]; o[1]=(f16)a[1]; o[2]=(f16)a[2]; o[3]=(f16)a[3];
            *(f16x4*)(ws + ((size_t)(rb * SEQ + t) * NW + tile * 16 + ln) * 16 + kg * 4) = o;
        }
        __syncthreads();
    }
}

// ===================== main RNN kernel (consumes ws) =====================
__global__ __launch_bounds__(NTH, 2) __attribute__((amdgpu_waves_per_eu(2, 2)))
void hgru_kernel(
    const f16* __restrict__ ws,
    const float* __restrict__ r_w, const float* __restrict__ r_b,
    const float* __restrict__ z_w, const float* __restrict__ z_b,
    const float* __restrict__ h_w0, const float* __restrict__ h_b0,
    const float* __restrict__ h_w1, const float* __restrict__ h_b1,
    const float* __restrict__ h_w2, const float* __restrict__ h_b2,
    float* __restrict__ out, float* __restrict__ hid_out)
{
    __shared__ __align__(16) f16   sh16[MR * SXS];  // h (f16 A-panel)
    __shared__ __align__(16) f16   srh[MR * SXS];   // r*h A-panel
    __shared__ __align__(16) f16   sy0[MR * SYS];   // mlp act1 (padded to 160)
    __shared__ __align__(16) f16   sy1[MR * SYS];   // mlp act2
    __shared__ __align__(16) float sz [MR * SZS];   // z gate f32
    __shared__ __align__(16) float shf[MR * SZS];   // master h state f32

    const int tid  = threadIdx.x;
    const int w    = tid >> 6;
    const int lane = tid & 63;
    const int ln   = lane & 15;
    const int kg   = lane >> 4;
    const int rb   = blockIdx.x;
    const int b0   = rb * MR;
    const int col  = w * 16 + ln;

    for (int i = tid; i < MR * SYS; i += NTH) { sy0[i] = (f16)0.f; sy1[i] = (f16)0.f; }
    for (int i = tid; i < MR * SXS; i += NTH) { sh16[i] = (f16)0.f; }
    for (int i = tid; i < MR * SZS; i += NTH) { shf[i] = 0.f; }

    // ---- register weight fragments (h-rows + MLP interior only) ----
    f16x8 wrh[4], wzh[4], w0h[4];
    #pragma unroll
    for (int kt = 0; kt < 4; ++kt) {
        f16x8 a, b, c;
        #pragma unroll
        for (int j = 0; j < 8; ++j) {
            const int k = DI + kt * 32 + kg * 8 + j;
            a[j] = (f16)r_w [(size_t)k * DH + col];
            b[j] = (f16)z_w [(size_t)k * DH + col];
            c[j] = (f16)h_w0[(size_t)k * DM + col];
        }
        wrh[kt] = a; wzh[kt] = b; w0h[kt] = c;
    }
    f16x8 w1f[5], w2f[5];
    #pragma unroll
    for (int kt = 0; kt < 5; ++kt) {
        f16x8 a, b;
        #pragma unroll
        for (int j = 0; j < 8; ++j) {
            const int k = kt * 32 + kg * 8 + j;
            const bool in = (k < DM);
            a[j] = in ? (f16)h_w1[(size_t)k * DM + col] : (f16)0.f;
            b[j] = in ? (f16)h_w2[(size_t)k * DH + col] : (f16)0.f;
        }
        w1f[kt] = a; w2f[kt] = b;
    }
    // ext: w==0 -> y0 tile8 (h-rows of h_w0); w==1 -> y1 tile8 (h_w1)
    f16x8 ext[5];
    #pragma unroll
    for (int kt = 0; kt < 5; ++kt) {
        f16x8 f;
        #pragma unroll
        for (int j = 0; j < 8; ++j) {
            const int k = kt * 32 + kg * 8 + j;
            float v = 0.f;
            if (w == 0 && kt < 4)      v = (float)h_w0[(size_t)(DI + k) * DM + 128 + ln];
            else if (w == 1 && k < DM) v = (float)h_w1[(size_t)k * DM + 128 + ln];
            f[j] = (f16)v;
        }
        ext[kt] = f;
    }

    const float b1r = r_b[col], b1z = z_b[col];
    const float b2  = h_b0[col], b3 = h_b1[col], b4 = h_b2[col];
    const float bext = (w == 0) ? h_b0[128 + ln] : (w == 1) ? h_b1[128 + ln] : 0.f;

    float* op[4];
    #pragma unroll
    for (int j = 0; j < 4; ++j)
        op[j] = out + (size_t)(b0 + 4 * kg + j) * SEQ * DH + col;

    // ---- ws C-in pointers (advance 400*16 elems per step) ----
    const size_t stepAdv = (size_t)NW * 16;
    const f16* pr = ws + ((size_t)rb * SEQ) * stepAdv + ((size_t)(      col) * 16 + kg * 4);
    const f16* pz = ws + ((size_t)rb * SEQ) * stepAdv + ((size_t)(128 + col) * 16 + kg * 4);
    const f16* pm = ws + ((size_t)rb * SEQ) * stepAdv + ((size_t)(256 + col) * 16 + kg * 4);
    const f16* p8 = ws + ((size_t)rb * SEQ) * stepAdv + ((size_t)(384 + ln ) * 16 + kg * 4);

    // prime: load C-ins for t=0
    f16x4 curR = *(const f16x4*)pr;
    f16x4 curZ = *(const f16x4*)pz;
    f16x4 curM = *(const f16x4*)pm;
    f16x4 cur8 = (w == 0) ? *(const f16x4*)p8 : f16x4{0,0,0,0};

    bar_lds();

    for (int t = 0; t < SEQ; ++t) {
        // prefetch next step's C-ins (a full step of latency cover)
        const size_t nadv = (t + 1 < SEQ) ? (size_t)(t + 1) * stepAdv : (size_t)t * stepAdv;
        const f16x4 nxtR = *(const f16x4*)(pr + nadv);
        const f16x4 nxtZ = *(const f16x4*)(pz + nadv);
        const f16x4 nxtM = *(const f16x4*)(pm + nadv);
        const f16x4 nxt8 = (w == 0) ? *(const f16x4*)(p8 + nadv) : f16x4{0,0,0,0};

        // ======== s1: r gate (short critical stage) ========
        f16x8 ha[4];
        #pragma unroll
        for (int kt = 0; kt < 4; ++kt)
            ha[kt] = *(const f16x8*)(sh16 + ln * SXS + kt * 32 + kg * 8);
        f32x4 ar = cvt4(curR);
        #pragma unroll
        for (int kt = 0; kt < 4; ++kt) ar = MFMA16(ha[kt], wrh[kt], ar);
        #pragma unroll
        for (int j = 0; j < 4; ++j) {
            const int m = 4 * kg + j;
            const float g = sigm(ar[j] + b1r);
            srh[m * SXS + col] = (f16)(g * shf[m * SZS + col]);
        }
        bar_lds(); // A

        // ======== s2: y0 (critical) + z h-part (shadow, reuses ha) ========
        f32x4 pzv = cvt4(curZ);
        #pragma unroll
        for (int kt = 0; kt < 4; ++kt) pzv = MFMA16(ha[kt], wzh[kt], pzv);

        f16x8 ra[4];
        #pragma unroll
        for (int kt = 0; kt < 4; ++kt)
            ra[kt] = *(const f16x8*)(srh + ln * SXS + kt * 32 + kg * 8);
        f32x4 a0 = cvt4(curM);
        #pragma unroll
        for (int kt = 0; kt < 4; ++kt) a0 = MFMA16(ra[kt], w0h[kt], a0);
        #pragma unroll
        for (int j = 0; j < 4; ++j)
            sy0[(4 * kg + j) * SYS + col] = (f16)fmaxf(a0[j] + b2, 0.f);
        if (w == 0) {
            f32x4 a8 = cvt4(cur8);
            #pragma unroll
            for (int kt = 0; kt < 4; ++kt) a8 = MFMA16(ra[kt], ext[kt], a8);
            #pragma unroll
            for (int j = 0; j < 4; ++j)
                sy0[(4 * kg + j) * SYS + 128 + ln] = (f16)fmaxf(a8[j] + bext, 0.f);
        }
        bar_lds(); // B

        // ======== s3: y1 (critical) + z sigmoid ========
        f16x8 ya[5];
        #pragma unroll
        for (int kt = 0; kt < 5; ++kt)
            ya[kt] = *(const f16x8*)(sy0 + ln * SYS + kt * 32 + kg * 8);
        f32x4 a1 = {0.f, 0.f, 0.f, 0.f};
        #pragma unroll
        for (int kt = 0; kt < 5; ++kt) a1 = MFMA16(ya[kt], w1f[kt], a1);
        #pragma unroll
        for (int j = 0; j < 4; ++j)
            sy1[(4 * kg + j) * SYS + col] = (f16)fmaxf(a1[j] + b3, 0.f);
        if (w == 1) {
            f32x4 a8 = {0.f, 0.f, 0.f, 0.f};
            #pragma unroll
            for (int kt = 0; kt < 5; ++kt) a8 = MFMA16(ya[kt], ext[kt], a8);
            #pragma unroll
            for (int j = 0; j < 4; ++j)
                sy1[(4 * kg + j) * SYS + 128 + ln] = (f16)fmaxf(a8[j] + bext, 0.f);
        }
        #pragma unroll
        for (int j = 0; j < 4; ++j)
            sz[(4 * kg + j) * SZS + col] = sigm(pzv[j] + b1z);
        bar_lds(); // C

        // ======== s4: h~ + h update ========
        f16x8 za[5];
        #pragma unroll
        for (int kt = 0; kt < 5; ++kt)
            za[kt] = *(const f16x8*)(sy1 + ln * SYS + kt * 32 + kg * 8);
        f32x4 a2 = {0.f, 0.f, 0.f, 0.f};
        #pragma unroll
        for (int kt = 0; kt < 5; ++kt) a2 = MFMA16(za[kt], w2f[kt], a2);
        #pragma unroll
        for (int j = 0; j < 4; ++j) {
            const int m = 4 * kg + j;
            const float ht = tanh_fast(a2[j] + b4);
            const float zz = sz[m * SZS + col];
            const float hn = (1.f - zz) * shf[m * SZS + col] + zz * ht;
            shf[m * SZS + col] = hn;
            sh16[m * SXS + col] = (f16)hn;
            *op[j] = hn; op[j] += DH;
        }
        bar_lds(); // D

        curR = nxtR; curZ = nxtZ; curM = nxtM; cur8 = nxt8;
    }

    for (int i = tid; i < MR * DH; i += NTH)
        hid_out[(size_t)(b0 + (i >> 7)) * DH + (i & 127)] = shf[(i >> 7) * SZS + (i & 127)];
}

// ===================== fallback (R8 monolithic) if ws too small =====================
__global__ __launch_bounds__(NTH, 2) __attribute__((amdgpu_waves_per_eu(2, 2)))
void hgru_fallback(
    const float* __restrict__ inputs,
    const float* __restrict__ r_w, const float* __restrict__ r_b,
    const float* __restrict__ z_w, const float* __restrict__ z_b,
    const float* __restrict__ h_w0, const float* __restrict__ h_b0,
    const float* __restrict__ h_w1, const float* __restrict__ h_b1,
    const float* __restrict__ h_w2, const float* __restrict__ h_b2,
    float* __restrict__ out, float* __restrict__ hid_out)
{
    __shared__ __align__(16) f16   sx [MR * SXS];
    __shared__ __align__(16) f16   sh16[MR * SXS];
    __shared__ __align__(16) f16   srh[MR * SXS];
    __shared__ __align__(16) f16   sy0[MR * SYS];
    __shared__ __align__(16) f16   sy1[MR * SYS];
    __shared__ __align__(16) float sz [MR * SZS];
    __shared__ __align__(16) float shf[MR * SZS];
    __shared__ __align__(16) float pg[256 * PGS];
    __shared__ __align__(16) float pm[DM  * PGS];

    const int tid  = threadIdx.x;
    const int w    = tid >> 6;
    const int lane = tid & 63;
    const int ln   = lane & 15;
    const int kg   = lane >> 4;
    const int b0   = blockIdx.x * MR;
    const int col  = w * 16 + ln;

    for (int i = tid; i < MR * SYS; i += NTH) { sy0[i] = (f16)0.f; sy1[i] = (f16)0.f; }
    for (int i = tid; i < MR * SXS; i += NTH) { sh16[i] = (f16)0.f; }
    for (int i = tid; i < MR * SZS; i += NTH) { shf[i] = 0.f; }

    f16x8 wrh[4], wzh[4], w0h[4], wrx[4], wzx[4], w0x[4];
    #pragma unroll
    for (int kt = 0; kt < 4; ++kt) {
        f16x8 a, b, c, d, e, f;
        #pragma unroll
        for (int j = 0; j < 8; ++j) {
            const int k = kt * 32 + kg * 8 + j;
            a[j] = (f16)r_w [(size_t)(DI + k) * DH + col];
            b[j] = (f16)z_w [(size_t)(DI + k) * DH + col];
            c[j] = (f16)h_w0[(size_t)(DI + k) * DM + col];
            d[j] = (f16)r_w [(size_t)k * DH + col];
            e[j] = (f16)z_w [(size_t)k * DH + col];
            f[j] = (f16)h_w0[(size_t)k * DM + col];
        }
        wrh[kt] = a; wzh[kt] = b; w0h[kt] = c; wrx[kt] = d; wzx[kt] = e; w0x[kt] = f;
    }
    f16x8 w1f[5], w2f[5];
    #pragma unroll
    for (int kt = 0; kt < 5; ++kt) {
        f16x8 a, b;
        #pragma unroll
        for (int j = 0; j < 8; ++j) {
            const int k = kt * 32 + kg * 8 + j;
            const bool in = (k < DM);
            a[j] = in ? (f16)h_w1[(size_t)k * DM + col] : (f16)0.f;
            b[j] = in ? (f16)h_w2[(size_t)k * DH + col] : (f16)0.f;
        }
        w1f[kt] = a; w2f[kt] = b;
    }
    f16x8 ext[5];
    #pragma unroll
    for (int kt = 0; kt < 5; ++kt) {
        f16x8 f;
        #pragma unroll
        for (int j = 0; j < 8; ++j) {
            const int k = kt * 32 + kg * 8 + j;
            float v = 0.f;
            if (w == 0 && kt < 4)      v = (float)h_w0[(size_t)(DI + k) * DM + 128 + ln];
            else if (w == 1 && k < DM) v = (float)h_w1[(size_t)k * DM + 128 + ln];
            else if (w == 2 && kt < 4) v = (float)h_w0[(size_t)k * DM + 128 + ln];
            f[j] = (f16)v;
        }
        ext[kt] = f;
    }

    const float b1r = r_b[col], b1z = z_b[col];
    const float b2  = h_b0[col], b3 = h_b1[col], b4 = h_b2[col];
    const float bext = (w == 0) ? h_b0[128 + ln] : (w == 1) ? h_b1[128 + ln] : 0.f;

    float* op[4];
    #pragma unroll
    for (int j = 0; j < 4; ++j)
        op[j] = out + (size_t)(b0 + 4 * kg + j) * SEQ * DH + col;

    const bool xldr = (tid < 256);
    const int  xrow = tid >> 4;
    const int  xseg = tid & 15;
    const float* __restrict__ xbase = inputs + (size_t)(b0 + (xrow & 15)) * SEQ * DI + xseg * 8;

    float4 xpA0 = {0,0,0,0}, xpA1 = {0,0,0,0};
    if (xldr) {
        const float4 a = ((const float4*)xbase)[0];
        const float4 b = ((const float4*)(xbase + 4))[0];
        f16x8 v; v[0]=(f16)a.x; v[1]=(f16)a.y; v[2]=(f16)a.z; v[3]=(f16)a.w;
                 v[4]=(f16)b.x; v[5]=(f16)b.y; v[6]=(f16)b.z; v[7]=(f16)b.w;
        *(f16x8*)(sx + xrow * SXS + xseg * 8) = v;
        xpA0 = ((const float4*)(xbase + (size_t)1 * DI))[0];
        xpA1 = ((const float4*)(xbase + (size_t)1 * DI + 4))[0];
    }
    bar_lds();
    {
        f16x8 xa[4];
        #pragma unroll
        for (int kt = 0; kt < 4; ++kt)
            xa[kt] = *(const f16x8*)(sx + ln * SXS + kt * 32 + kg * 8);
        f32x4 a = {0,0,0,0};
        #pragma unroll
        for (int kt = 0; kt < 4; ++kt) a = MFMA16(xa[kt], wrx[kt], a);
        *(f32x4*)(pg + (unsigned)col * PGS + kg * 4) = a;
        f32x4 b = {0,0,0,0};
        #pragma unroll
        for (int kt = 0; kt < 4; ++kt) b = MFMA16(xa[kt], wzx[kt], b);
        *(f32x4*)(pg + (unsigned)(128 + col) * PGS + kg * 4) = b;
        f32x4 c = {0,0,0,0};
        #pragma unroll
        for (int kt = 0; kt < 4; ++kt) c = MFMA16(xa[kt], w0x[kt], c);
        *(f32x4*)(pm + (unsigned)col * PGS + kg * 4) = c;
        if (w == 2) {
            f32x4 d = {0,0,0,0};
            #pragma unroll
            for (int kt = 0; kt < 4; ++kt) d = MFMA16(xa[kt], ext[kt], d);
            *(f32x4*)(pm + (unsigned)(128 + ln) * PGS + kg * 4) = d;
        }
    }
    bar_lds();

    for (int t = 0; t < SEQ; ++t) {
        float4 xpB0, xpB1;
        if (xldr) {
            const int tn = (t + 2 < SEQ) ? t + 2 : SEQ - 1;
            xpB0 = ((const float4*)(xbase + (size_t)tn * DI))[0];
            xpB1 = ((const float4*)(xbase + (size_t)tn * DI + 4))[0];
        }
        f16x8 ha[4];
        #pragma unroll
        for (int kt = 0; kt < 4; ++kt)
            ha[kt] = *(const f16x8*)(sh16 + ln * SXS + kt * 32 + kg * 8);
        f32x4 ar = *(const f32x4*)(pg + (unsigned)col * PGS + kg * 4);
        #pragma unroll
        for (int kt = 0; kt < 4; ++kt) ar = MFMA16(ha[kt], wrh[kt], ar);
        #pragma unroll
        for (int j = 0; j < 4; ++j) {
            const int m = 4 * kg + j;
            const float g = sigm(ar[j] + b1r);
            srh[m * SXS + col] = (f16)(g * shf[m * SZS + col]);
        }
        bar_lds();

        f32x4 pzv = *(const f32x4*)(pg + (unsigned)(128 + col) * PGS + kg * 4);
        #pragma unroll
        for (int kt = 0; kt < 4; ++kt) pzv = MFMA16(ha[kt], wzh[kt], pzv);
        f16x8 ra[4];
        #pragma unroll
        for (int kt = 0; kt < 4; ++kt)
            ra[kt] = *(const f16x8*)(srh + ln * SXS + kt * 32 + kg * 8);
        f32x4 a0 = *(const f32x4*)(pm + (unsigned)col * PGS + kg * 4);
        #pragma unroll
        for (int kt = 0; kt < 4; ++kt) a0 = MFMA16(ra[kt], w0h[kt], a0);
        #pragma unroll
        for (int j = 0; j < 4; ++j)
            sy0[(4 * kg + j) * SYS + col] = (f16)fmaxf(a0[j] + b2, 0.f);
        if (w == 0) {
            f32x4 a8 = *(const f32x4*)(pm + (unsigned)(128 + ln) * PGS + kg * 4);
            #pragma unroll
            for (int kt = 0; kt < 4; ++kt) a8 = MFMA16(ra[kt], ext[kt], a8);
            #pragma unroll
            for (int j = 0; j < 4; ++j)
                sy0[(4 * kg + j) * SYS + 128 + ln] = (f16)fmaxf(a8[j] + bext, 0.f);
        }
        if (xldr) {
            f16x8 v; v[0]=(f16)xpA0.x; v[1]=(f16)xpA0.y; v[2]=(f16)xpA0.z; v[3]=(f16)xpA0.w;
                     v[4]=(f16)xpA1.x; v[5]=(f16)xpA1.y; v[6]=(f16)xpA1.z; v[7]=(f16)xpA1.w;
            *(f16x8*)(sx + xrow * SXS + xseg * 8) = v;
        }
        bar_lds();

        f16x8 ya[5];
        #pragma unroll
        for (int kt = 0; kt < 5; ++kt)
            ya[kt] = *(const f16x8*)(sy0 + ln * SYS + kt * 32 + kg * 8);
        f32x4 a1 = {0,0,0,0};
        #pragma unroll
        for (int kt = 0; kt < 5; ++kt) a1 = MFMA16(ya[kt], w1f[kt], a1);
        #pragma unroll
        for (int j = 0; j < 4; ++j)
            sy1[(4 * kg + j) * SYS + col] = (f16)fmaxf(a1[j] + b3, 0.f);
        if (w == 1) {
            f32x4 a8 = {0,0,0,0};
            #pragma unroll
            for (int kt = 0; kt < 5; ++kt) a8 = MFMA16(ya[kt], ext[kt], a8);
            #pragma unroll
            for (int j = 0; j < 4; ++j)
                sy1[(4 * kg + j) * SYS + 128 + ln] = (f16)fmaxf(a8[j] + bext, 0.f);
        }
        #pragma unroll
        for (int j = 0; j < 4; ++j)
            sz[(4 * kg + j) * SZS + col] = sigm(pzv[j] + b1z);
        f16x8 xa[4];
        #pragma unroll
        for (int kt = 0; kt < 4; ++kt)
            xa[kt] = *(const f16x8*)(sx + ln * SXS + kt * 32 + kg * 8);
        {
            f32x4 a = {0,0,0,0};
            #pragma unroll
            for (int kt = 0; kt < 4; ++kt) a = MFMA16(xa[kt], wrx[kt], a);
            *(f32x4*)(pg + (unsigned)col * PGS + kg * 4) = a;
            f32x4 b = {0,0,0,0};
            #pragma unroll
            for (int kt = 0; kt < 4; ++kt) b = MFMA16(xa[kt], wzx[kt], b);
            *(f32x4*)(pg + (unsigned)(128 + col) * PGS + kg * 4) = b;
        }
        bar_lds();

        f16x8 za[5];
        #pragma unroll
        for (int kt = 0; kt < 5; ++kt)
            za[kt] = *(const f16x8*)(sy1 + ln * SYS + kt * 32 + kg * 8);
        f32x4 a2 = {0,0,0,0};
        #pragma unroll
        for (int kt = 0; kt < 5; ++kt) a2 = MFMA16(za[kt], w2f[kt], a2);
        {
            f32x4 a = {0,0,0,0};
            #pragma unroll
            for (int kt = 0; kt < 4; ++kt) a = MFMA16(xa[kt], w0x[kt], a);
            *(f32x4*)(pm + (unsigned)col * PGS + kg * 4) = a;
            if (w == 2) {
                f32x4 d = {0,0,0,0};
                #pragma unroll
                for (int kt = 0; kt < 4; ++kt) d = MFMA16(xa[kt], ext[kt], d);
                *(f32x4*)(pm + (unsigned)(128 + ln) * PGS + kg * 4) = d;
            }
        }
        #pragma unroll
        for (int j = 0; j < 4; ++j) {
            const int m = 4 * kg + j;
            const float ht = tanh_fast(a2[j] + b4);
            const float zz = sz[m * SZS + col];
            const float hn = (1.f - zz) * shf[m * SZS + col] + zz * ht;
            shf[m * SZS + col] = hn;
            sh16[m * SXS + col] = (f16)hn;
            *op[j] = hn; op[j] += DH;
        }
        bar_lds();
        xpA0 = xpB0; xpA1 = xpB1;
    }

    for (int i = tid; i < MR * DH; i += NTH)
        hid_out[(size_t)(b0 + (i >> 7)) * DH + (i & 127)] = shf[(i >> 7) * SZS + (i & 127)];
}

extern "C" void kernel_launch(void* const* d_in, const int* in_sizes, int n_in,
                              void* d_out, int out_size, void* d_ws, size_t ws_size,
                              hipStream_t stream) {
    const float* inputs = (const float*)d_in[0];
    const float* r_w  = (const float*)d_in[1];
    const float* r_b  = (const float*)d_in[2];
    const float* z_w  = (const float*)d_in[3];
    const float* z_b  = (const float*)d_in[4];
    const float* h_w0 = (const float*)d_in[5];
    const float* h_b0 = (const float*)d_in[6];
    const float* h_w1 = (const float*)d_in[7];
    const float* h_b1 = (const float*)d_in[8];
    const float* h_w2 = (const float*)d_in[9];
    const float* h_b2 = (const float*)d_in[10];

    float* out = (float*)d_out;
    float* hid = out + (size_t)BATCH * SEQ * DH;

    if (ws_size >= WS_ELEMS * sizeof(f16)) {
        f16* ws = (f16*)d_ws;
        hipLaunchKernelGGL(xproj_kernel, dim3(16 * 32), dim3(512), 0, stream,
                           inputs, r_w, z_w, h_w0, ws);
        hipLaunchKernelGGL(hgru_kernel, dim3(BATCH / MR), dim3(NTH), 0, stream,
                           ws, r_w, r_b, z_w, z_b,
                           h_w0, h_b0, h_w1, h_b1, h_w2, h_b2,
                           out, hid);
    } else {
        hipLaunchKernelGGL(hgru_fallback, dim3(BATCH / MR), dim3(NTH), 0, stream,
                           inputs, r_w, r_b, z_w, z_b,
                           h_w0, h_b0, h_w1, h_b1, h_w2, h_b2,
                           out, hid);
    }
}